// Round 1
// baseline (183.316 us; speedup 1.0000x reference)
//
#include <hip/hip_runtime.h>
#include <hip/hip_bf16.h>

// ---------------------------------------------------------------------------
// EuclideanDeconf: out[b,c] = (2*dot(x[b],W[c]) - ||x[b]||^2 - ||W[c]||^2) / D
// Strategy: fp32 -> bf16 convert + row-sq pass, then m97-style bf16 MFMA GEMM
// (B^T layout: both operands K-contiguous) with fused epilogue.
// ---------------------------------------------------------------------------

typedef __bf16 bf16x8 __attribute__((ext_vector_type(8)));
typedef float f32x4 __attribute__((ext_vector_type(4)));
typedef unsigned short ushort8 __attribute__((ext_vector_type(8)));

#define BDIM 4096
#define DDIM 4096
#define CDIM 1024

#define TM 128
#define TN 64
#define TK 32

__device__ __forceinline__ unsigned short f2bf(float f) {
    unsigned int u = __float_as_uint(f);
    unsigned int rounding = 0x7FFFu + ((u >> 16) & 1u);  // round-to-nearest-even
    return (unsigned short)((u + rounding) >> 16);
}

// One block per row. Converts fp32 row -> bf16 row (16B stores) and writes
// sum of squares of the row (fp32) to sq[row].
__global__ __launch_bounds__(256) void cvt_rowsq(
    const float* __restrict__ x, const float* __restrict__ W,
    unsigned short* __restrict__ xb, unsigned short* __restrict__ wb,
    float* __restrict__ xsq, float* __restrict__ wsq, int Dn, int Bn)
{
    int row = blockIdx.x;
    const float* src;
    unsigned short* dst;
    float* sq;
    if (row < Bn) {
        src = x + (size_t)row * Dn;
        dst = xb + (size_t)row * Dn;
        sq = xsq + row;
    } else {
        int r = row - Bn;
        src = W + (size_t)r * Dn;
        dst = wb + (size_t)r * Dn;
        sq = wsq + r;
    }

    const float4* s4 = (const float4*)src;
    ushort8* d8 = (ushort8*)dst;
    float acc = 0.f;
    // 256 threads, 8 floats each per pass
    for (int g = threadIdx.x; g * 8 < Dn; g += 256) {
        float4 f0 = s4[g * 2];
        float4 f1 = s4[g * 2 + 1];
        acc += f0.x * f0.x + f0.y * f0.y + f0.z * f0.z + f0.w * f0.w;
        acc += f1.x * f1.x + f1.y * f1.y + f1.z * f1.z + f1.w * f1.w;
        ushort8 o;
        o[0] = f2bf(f0.x); o[1] = f2bf(f0.y); o[2] = f2bf(f0.z); o[3] = f2bf(f0.w);
        o[4] = f2bf(f1.x); o[5] = f2bf(f1.y); o[6] = f2bf(f1.z); o[7] = f2bf(f1.w);
        d8[g] = o;
    }
    // wave reduce (64 lanes), then cross-wave via LDS
    #pragma unroll
    for (int off = 32; off > 0; off >>= 1) acc += __shfl_down(acc, off);
    __shared__ float red[4];
    if ((threadIdx.x & 63) == 0) red[threadIdx.x >> 6] = acc;
    __syncthreads();
    if (threadIdx.x == 0) *sq = red[0] + red[1] + red[2] + red[3];
}

// GEMM: cross[b,c] = sum_d xb[b,d]*wb[c,d]; out = (2*cross - xsq - wsq)/D.
// 128x64x32 tile, 256 threads (4 waves, 2x2), wave = 64x32 = 4x2 MFMA tiles.
__global__ __launch_bounds__(256, 2) void gemm_eucl(
    const unsigned short* __restrict__ xb,  // [B, D] bf16 bits
    const unsigned short* __restrict__ wb,  // [C, D] bf16 bits
    const float* __restrict__ xsq,          // [B]
    const float* __restrict__ wsq,          // [C]
    float* __restrict__ out,                // [B, C] fp32
    int Dn, int Cn)
{
    __shared__ unsigned short As[TM * TK];  // 8 KB, contiguous lane-order (no pad)
    __shared__ unsigned short Bs[TN * TK];  // 4 KB

    const int tid = threadIdx.x;
    const int lane = tid & 63;
    const int wid = tid >> 6;
    const int bm = blockIdx.x * TM;
    const int bn = blockIdx.y * TN;
    const int wm = (wid >> 1) * 64;  // wave row offset: 0 or 64
    const int wn = (wid & 1) * 32;   // wave col offset: 0 or 32

    // staging: chunk c (16B = 8 bf16) -> LDS offset c*8 elems; row=c>>2, col8=(c&3)*8
    const int acol = (tid & 3) * 8;
    const unsigned short* ga0 = xb + (size_t)(bm + (tid >> 2)) * Dn + acol;
    const unsigned short* ga1 = xb + (size_t)(bm + (tid >> 2) + 64) * Dn + acol;
    const unsigned short* gb  = wb + (size_t)(bn + (tid >> 2)) * Dn + acol;

    // fragment addresses (A[m=lane&15][k=(lane>>4)*8+j], same for B with n)
    const int kb = (lane >> 4) * 8;
    const int am = wm + (lane & 15);
    const int bnl = wn + (lane & 15);

    f32x4 acc[4][2] = {};

    for (int k0 = 0; k0 < Dn; k0 += TK) {
        __syncthreads();  // LDS consumed by previous iter's MFMAs
        __builtin_amdgcn_global_load_lds(
            (__attribute__((address_space(1))) const void*)ga0,
            (__attribute__((address_space(3))) void*)(&As[tid * 8]), 16, 0, 0);
        __builtin_amdgcn_global_load_lds(
            (__attribute__((address_space(1))) const void*)ga1,
            (__attribute__((address_space(3))) void*)(&As[tid * 8 + 2048]), 16, 0, 0);
        __builtin_amdgcn_global_load_lds(
            (__attribute__((address_space(1))) const void*)gb,
            (__attribute__((address_space(3))) void*)(&Bs[tid * 8]), 16, 0, 0);
        ga0 += TK; ga1 += TK; gb += TK;
        __syncthreads();  // drain global_load_lds (compiler emits vmcnt(0))

        bf16x8 af[4], bfr[2];
        #pragma unroll
        for (int i = 0; i < 4; ++i)
            af[i] = *(const bf16x8*)&As[(am + i * 16) * TK + kb];
        #pragma unroll
        for (int j = 0; j < 2; ++j)
            bfr[j] = *(const bf16x8*)&Bs[(bnl + j * 16) * TK + kb];
        #pragma unroll
        for (int i = 0; i < 4; ++i)
            #pragma unroll
            for (int j = 0; j < 2; ++j)
                acc[i][j] = __builtin_amdgcn_mfma_f32_16x16x32_bf16(
                    af[i], bfr[j], acc[i][j], 0, 0, 0);
    }

    // epilogue: C/D layout col=lane&15, row=(lane>>4)*4+r
    const float invD = 1.0f / (float)Dn;
    const int row_l = (lane >> 4) * 4;
    const int col_l = lane & 15;
    #pragma unroll
    for (int i = 0; i < 4; ++i) {
        #pragma unroll
        for (int j = 0; j < 2; ++j) {
            int gn = bn + wn + j * 16 + col_l;
            float wv = wsq[gn];
            #pragma unroll
            for (int r = 0; r < 4; ++r) {
                int gm = bm + wm + i * 16 + row_l + r;
                out[(size_t)gm * Cn + gn] = (2.0f * acc[i][j][r] - xsq[gm] - wv) * invD;
            }
        }
    }
}

// Safety net if ws_size is too small for bf16 staging (slow but correct).
__global__ void fallback_kernel(const float* __restrict__ x, const float* __restrict__ W,
                                float* __restrict__ out, int Dn, int Cn)
{
    int c = blockIdx.x * blockDim.x + threadIdx.x;
    int b = blockIdx.y;
    if (c >= Cn) return;
    const float* xr = x + (size_t)b * Dn;
    const float* wr = W + (size_t)c * Dn;
    float xs = 0.f, ws = 0.f, cr = 0.f;
    for (int d = 0; d < Dn; ++d) {
        float xv = xr[d], wv = wr[d];
        xs += xv * xv; ws += wv * wv; cr += xv * wv;
    }
    out[(size_t)b * Cn + c] = (2.0f * cr - xs - ws) / (float)Dn;
}

extern "C" void kernel_launch(void* const* d_in, const int* in_sizes, int n_in,
                              void* d_out, int out_size, void* d_ws, size_t ws_size,
                              hipStream_t stream) {
    const float* x = (const float*)d_in[0];   // [B, D] fp32
    const float* W = (const float*)d_in[1];   // [C, D] fp32
    float* out = (float*)d_out;               // [B, C] fp32

    const int Bn = BDIM, Dn = DDIM, Cn = CDIM;

    size_t need = (size_t)(Bn + Cn) * Dn * sizeof(unsigned short)
                + (size_t)(Bn + Cn) * sizeof(float);
    if (ws_size < need) {
        fallback_kernel<<<dim3(Cn / 256, Bn), 256, 0, stream>>>(x, W, out, Dn, Cn);
        return;
    }

    unsigned short* xb = (unsigned short*)d_ws;            // 32 MB
    unsigned short* wb = xb + (size_t)Bn * Dn;             // 8 MB
    float* xsq = (float*)(wb + (size_t)Cn * Dn);           // 16 KB
    float* wsq = xsq + Bn;                                 // 4 KB

    cvt_rowsq<<<Bn + Cn, 256, 0, stream>>>(x, W, xb, wb, xsq, wsq, Dn, Bn);
    gemm_eucl<<<dim3(Bn / TM, Cn / TN), 256, 0, stream>>>(xb, wb, xsq, wsq, out, Dn, Cn);
}